// Round 5
// baseline (362.689 us; speedup 1.0000x reference)
//
#include <hip/hip_runtime.h>

// Problem constants
#define BATCH 2
#define P1 5308416      // 48^4
#define NX 10616832     // 2 * 48^4  (x elements, single channel)
#define P2 331776       // 24^4
#define NPOS 663552     // 2 * 24^4  (positions in y2 per channel)
#define N2CH 663552.0   // BN2 per-channel count
#define NZCH 10616832.0 // BN3 per-channel count (2 * 48^4)
#define EPS 1e-5
#define SLOPE 0.01f
#define NBANK 16

typedef float f32x2 __attribute__((ext_vector_type(2)));

// ws layout (bytes):
//   0    : dx[16][2]  doubles (sum_x, sumsq_x banks)        256 B
//   256  : d2[16][12] doubles (y2 per-ch sum[6], sumsq[6]) 1536 B
//   1792 : d3[16][27] doubles (S[6], G_triangle[21])       3456 B
//   5248 : params float[18]  (a2[6], c2[6], a3[3], c3[3])
//   8192 : y2 float[2][6][331776]  (15.93 MB)

__device__ __forceinline__ float lrelu(float v) { return v >= 0.f ? v : SLOPE * v; }

__device__ __forceinline__ double wred(double v) {
#pragma unroll
    for (int off = 32; off > 0; off >>= 1) v += __shfl_down(v, off, 64);
    return v;
}

// ---------------- K1: global sum / sumsq of x ----------------
__global__ __launch_bounds__(256) void k1_stats_x(const float4* __restrict__ x4,
                                                  double* __restrict__ dx) {
    int gid = blockIdx.x * 256 + threadIdx.x;
    double s = 0.0, q = 0.0;
#pragma unroll 1
    for (int i = gid; i < NX / 4; i += 1296 * 256) {
        float4 v = x4[i];
        s += (double)v.x + (double)v.y + (double)v.z + (double)v.w;
        q += (double)v.x * v.x + (double)v.y * v.y + (double)v.z * v.z + (double)v.w * v.w;
    }
    s = wred(s); q = wred(q);
    __shared__ double lds[4][2];
    int lane = threadIdx.x & 63, wv = threadIdx.x >> 6;
    if (lane == 0) { lds[wv][0] = s; lds[wv][1] = q; }
    __syncthreads();
    if (threadIdx.x < 2) {
        double t = lds[0][threadIdx.x] + lds[1][threadIdx.x] + lds[2][threadIdx.x] + lds[3][threadIdx.x];
        atomicAdd(&dx[(blockIdx.x & (NBANK - 1)) * 2 + threadIdx.x], t);
    }
}

// ------- K2: lrelu(bn1(conv1(x))) -> conv2 (k2 s2) -> y2, + BN2 raw stats -------
__global__ __launch_bounds__(256) void k2_conv(const float* __restrict__ x,
                                               const float* __restrict__ w1,
                                               const float* __restrict__ g1,
                                               const float* __restrict__ b1,
                                               const float* __restrict__ w2,
                                               const double* __restrict__ dx,
                                               float* __restrict__ y2,
                                               double* __restrict__ d2) {
    // bn1 folded affine: y1n = lrelu(a1[c]*x + c1[c])
    double sx = 0.0, qx = 0.0;
#pragma unroll
    for (int bk = 0; bk < NBANK; ++bk) { sx += dx[bk * 2]; qx += dx[bk * 2 + 1]; }
    double mux = sx / (double)NX;
    double vax = qx / (double)NX - mux * mux;
    float a1[3], c1[3];
#pragma unroll
    for (int c = 0; c < 3; ++c) {
        double w = (double)w1[c];
        double inv = 1.0 / sqrt(w * w * vax + EPS);
        double a = w * (double)g1[c] * inv;
        a1[c] = (float)a;
        c1[c] = (float)((double)b1[c] - mux * a);
    }

    double dsum[6] = {0, 0, 0, 0, 0, 0}, dsq[6] = {0, 0, 0, 0, 0, 0};
#pragma unroll 1
    for (int it = 0; it < 4; ++it) {
        int t = blockIdx.x * 256 + threadIdx.x + it * 165888;
        int b = t / P2, rem = t % P2;
        int l0 = rem % 24, t1 = rem / 24;
        int k0 = t1 % 24, t2 = t1 / 24;
        int j0 = t2 % 24, i0 = t2 / 24;
        const float* xb = x + (size_t)b * P1 + (size_t)i0 * 221184 + j0 * 4608 + k0 * 96 + l0 * 2;
        float acc[6] = {0, 0, 0, 0, 0, 0};
#pragma unroll
        for (int p = 0; p < 2; ++p)
#pragma unroll
            for (int q = 0; q < 2; ++q)
#pragma unroll
                for (int r = 0; r < 2; ++r) {
                    const f32x2 xv = *(const f32x2*)(xb + p * 110592 + q * 2304 + r * 48);
#pragma unroll
                    for (int s = 0; s < 2; ++s) {
                        float xs = xv[s];
                        int m = p * 8 + q * 4 + r * 2 + s;
#pragma unroll
                        for (int c = 0; c < 3; ++c) {
                            float tt = lrelu(a1[c] * xs + c1[c]);
#pragma unroll
                            for (int o = 0; o < 6; ++o) acc[o] += w2[o * 48 + c * 16 + m] * tt;
                        }
                    }
                }
#pragma unroll
        for (int o = 0; o < 6; ++o) {
            y2[(size_t)(b * 6 + o) * P2 + rem] = acc[o];
            dsum[o] += (double)acc[o];
            dsq[o] += (double)acc[o] * acc[o];
        }
    }
    // block-reduce 12 doubles, banked atomics
    __shared__ double lds[4][12];
    int lane = threadIdx.x & 63, wv = threadIdx.x >> 6;
#pragma unroll
    for (int o = 0; o < 6; ++o) {
        double v = wred(dsum[o]); if (lane == 0) lds[wv][o] = v;
        v = wred(dsq[o]);         if (lane == 0) lds[wv][6 + o] = v;
    }
    __syncthreads();
    if (threadIdx.x < 12) {
        double t = lds[0][threadIdx.x] + lds[1][threadIdx.x] + lds[2][threadIdx.x] + lds[3][threadIdx.x];
        atomicAdd(&d2[(blockIdx.x & (NBANK - 1)) * 12 + threadIdx.x], t);
    }
}

// ------- K3: Gram/S of y2n = lrelu(bn2(y2))  (for closed-form BN3 stats) -------
__global__ __launch_bounds__(256) void k3_gram(const float* __restrict__ y2,
                                               const float* __restrict__ g2,
                                               const float* __restrict__ b2,
                                               const double* __restrict__ d2,
                                               double* __restrict__ d3) {
    float a2[6], c2[6];
#pragma unroll
    for (int c = 0; c < 6; ++c) {
        double s = 0.0, q = 0.0;
#pragma unroll
        for (int bk = 0; bk < NBANK; ++bk) { s += d2[bk * 12 + c]; q += d2[bk * 12 + 6 + c]; }
        double mu = s / N2CH;
        double va = q / N2CH - mu * mu;
        double a = (double)g2[c] / sqrt(va + EPS);
        a2[c] = (float)a;
        c2[c] = (float)((double)b2[c] - mu * a);
    }
    double S[6] = {0, 0, 0, 0, 0, 0};
    double G[21] = {0};
#pragma unroll 1
    for (int it = 0; it < 4; ++it) {
        int t = blockIdx.x * 256 + threadIdx.x + it * 165888;
        int b = t / P2, rem = t % P2;
        float yn[6];
#pragma unroll
        for (int c = 0; c < 6; ++c) {
            float v = y2[(size_t)(b * 6 + c) * P2 + rem];
            yn[c] = lrelu(a2[c] * v + c2[c]);
            S[c] += (double)yn[c];
        }
        int gi = 0;
#pragma unroll
        for (int c = 0; c < 6; ++c)
#pragma unroll
            for (int cc = c; cc < 6; ++cc) { G[gi] += (double)yn[c] * yn[cc]; ++gi; }
    }
    __shared__ double lds[4][27];
    int lane = threadIdx.x & 63, wv = threadIdx.x >> 6;
#pragma unroll
    for (int i = 0; i < 6; ++i) { double v = wred(S[i]); if (lane == 0) lds[wv][i] = v; }
#pragma unroll
    for (int i = 0; i < 21; ++i) { double v = wred(G[i]); if (lane == 0) lds[wv][6 + i] = v; }
    __syncthreads();
    if (threadIdx.x < 27) {
        double t = lds[0][threadIdx.x] + lds[1][threadIdx.x] + lds[2][threadIdx.x] + lds[3][threadIdx.x];
        atomicAdd(&d3[(blockIdx.x & (NBANK - 1)) * 27 + threadIdx.x], t);
    }
}

// ------- K4: finalize bn2 affine + closed-form BN3 affine (tiny) -------
__global__ void k4_params(const double* __restrict__ d2, const double* __restrict__ d3,
                          const float* __restrict__ wt,
                          const float* __restrict__ g2v, const float* __restrict__ b2v,
                          const float* __restrict__ g3, const float* __restrict__ b3,
                          float* __restrict__ params) {
    __shared__ double S[6], G[21], s2[12];
    int t = threadIdx.x;
    if (t < 27) {
        double a = 0.0;
        for (int bk = 0; bk < NBANK; ++bk) a += d3[bk * 27 + t];
        if (t < 6) S[t] = a; else G[t - 6] = a;
    }
    if (t >= 32 && t < 44) {
        double a = 0.0;
        for (int bk = 0; bk < NBANK; ++bk) a += d2[bk * 12 + (t - 32)];
        s2[t - 32] = a;
    }
    __syncthreads();
    if (t < 6) {
        int c = t;
        double mu = s2[c] / N2CH;
        double va = s2[6 + c] / N2CH - mu * mu;
        double a = (double)g2v[c] / sqrt(va + EPS);
        params[c] = (float)a;
        params[6 + c] = (float)((double)b2v[c] - mu * a);
    }
    if (t < 3) {
        int o = t;
        double sumz = 0.0, ssq = 0.0;
        for (int c = 0; c < 6; ++c) {
            double wsum = 0.0;
            for (int m = 0; m < 16; ++m) wsum += (double)wt[c * 48 + o * 16 + m];
            sumz += S[c] * wsum;
        }
        for (int c = 0; c < 6; ++c)
            for (int cc = 0; cc < 6; ++cc) {
                double ww = 0.0;
                for (int m = 0; m < 16; ++m) ww += (double)wt[c * 48 + o * 16 + m] * wt[cc * 48 + o * 16 + m];
                int aa = c < cc ? c : cc, bb = c < cc ? cc : c;
                int gidx = aa * 6 - aa * (aa + 1) / 2 + bb;
                ssq += G[gidx] * ww;
            }
        double mu = sumz / NZCH;
        double va = ssq / NZCH - mu * mu;
        double a = (double)g3[o] / sqrt(va + EPS);
        params[12 + o] = (float)a;
        params[15 + o] = (float)((double)b3[o] - mu * a);
    }
}

// ------- K5: y2 -> bn2+lrelu -> convT expand -> bn3 -> sigmoid -> out -------
__global__ __launch_bounds__(256) void k5_expand(const float* __restrict__ y2,
                                                 const float* __restrict__ wt,
                                                 const float* __restrict__ params,
                                                 float* __restrict__ out) {
    int t = blockIdx.x * 256 + threadIdx.x;
    int b = t / P2, rem = t % P2;
    int l0 = rem % 24, t1 = rem / 24;
    int k0 = t1 % 24, t2 = t1 / 24;
    int j0 = t2 % 24, i0 = t2 / 24;
    float yn[6];
#pragma unroll
    for (int c = 0; c < 6; ++c) {
        float v = y2[(size_t)(b * 6 + c) * P2 + rem];
        yn[c] = lrelu(params[c] * v + params[6 + c]);
    }
    size_t obase = (size_t)b * 15925248 + (size_t)i0 * 221184 + j0 * 4608 + k0 * 96 + l0 * 2;
#pragma unroll
    for (int o = 0; o < 3; ++o) {
        float a3 = params[12 + o], c3 = params[15 + o];
#pragma unroll
        for (int p = 0; p < 2; ++p)
#pragma unroll
            for (int q = 0; q < 2; ++q)
#pragma unroll
                for (int r = 0; r < 2; ++r) {
                    f32x2 res;
#pragma unroll
                    for (int s = 0; s < 2; ++s) {
                        int m = p * 8 + q * 4 + r * 2 + s;
                        float z = 0.f;
#pragma unroll
                        for (int c = 0; c < 6; ++c) z += yn[c] * wt[c * 48 + o * 16 + m];
                        float v = a3 * z + c3;
                        res[s] = 1.f / (1.f + __expf(-v));
                    }
                    __builtin_nontemporal_store(res, (f32x2*)(out + obase + (size_t)o * P1 + p * 110592 + q * 2304 + r * 48));
                }
    }
}

extern "C" void kernel_launch(void* const* d_in, const int* in_sizes, int n_in,
                              void* d_out, int out_size, void* d_ws, size_t ws_size,
                              hipStream_t stream) {
    const float* x  = (const float*)d_in[0];
    const float* w1 = (const float*)d_in[1];
    const float* g1 = (const float*)d_in[2];
    const float* b1 = (const float*)d_in[3];
    const float* w2 = (const float*)d_in[4];
    const float* g2 = (const float*)d_in[5];
    const float* b2 = (const float*)d_in[6];
    const float* wt = (const float*)d_in[7];
    const float* g3 = (const float*)d_in[8];
    const float* b3 = (const float*)d_in[9];
    float* out = (float*)d_out;

    char* ws = (char*)d_ws;
    double* dx     = (double*)(ws);
    double* d2     = (double*)(ws + 256);
    double* d3     = (double*)(ws + 1792);
    float*  params = (float*)(ws + 5248);
    float*  y2     = (float*)(ws + 8192);

    (void)hipMemsetAsync(d_ws, 0, 5248, stream);
    k1_stats_x<<<1296, 256, 0, stream>>>((const float4*)x, dx);
    k2_conv<<<648, 256, 0, stream>>>(x, w1, g1, b1, w2, dx, y2, d2);
    k3_gram<<<648, 256, 0, stream>>>(y2, g2, b2, d2, d3);
    k4_params<<<1, 64, 0, stream>>>(d2, d3, wt, g2, b2, g3, b3, params);
    k5_expand<<<2592, 256, 0, stream>>>(y2, wt, params, out);
}

// Round 10
// 290.375 us; speedup vs baseline: 1.2490x; 1.2490x over previous
//
#include <hip/hip_runtime.h>

// Problem constants
#define P1 5308416      // 48^4
#define NX 10616832     // 2 * 48^4  (x elements, single channel)
#define P2 331776       // 24^4
#define N2CH 663552.0   // BN2 per-channel count (2 * 24^4)
#define NZCH 10616832.0 // BN3 per-channel count (2 * 48^4)
#define EPS 1e-5
#define SLOPE 0.01f
#define NBANK 16

typedef float f32x2 __attribute__((ext_vector_type(2)));
typedef float f32x4 __attribute__((ext_vector_type(4)));

// ws layout (bytes):
//   0    : dx[16][2]  doubles (sum_x, sumsq_x banks)        256 B
//   256  : d2[16][12] doubles (y2 per-ch sum[6], sumsq[6]) 1536 B
//   1792 : d3[16][27] doubles (S[6], G_triangle[21])       3456 B
//   5248 : params float[18]  (a2[6], c2[6], a3[3], c3[3])
//   8192 : y2 float[2][6][331776]  (15.93 MB)

__device__ __forceinline__ float lrelu(float v) { return v >= 0.f ? v : SLOPE * v; }

__device__ __forceinline__ float wredf(float v) {
#pragma unroll
    for (int off = 32; off > 0; off >>= 1) v += __shfl_down(v, off, 64);
    return v;
}

// ---------------- K1: global sum / sumsq of x (f32 partials, f64 atomics) ----------------
__global__ __launch_bounds__(256) void k1_stats_x(const f32x4* __restrict__ x4,
                                                  double* __restrict__ dx) {
    int gid = blockIdx.x * 256 + threadIdx.x;   // 331776 threads, 8 float4 each
    float s = 0.f, q = 0.f;
#pragma unroll
    for (int k = 0; k < 8; ++k) {
        f32x4 v = x4[gid + k * 331776];
        s += v.x + v.y + v.z + v.w;
        q += v.x * v.x + v.y * v.y + v.z * v.z + v.w * v.w;
    }
    s = wredf(s); q = wredf(q);
    __shared__ float lds[4][2];
    int lane = threadIdx.x & 63, wv = threadIdx.x >> 6;
    if (lane == 0) { lds[wv][0] = s; lds[wv][1] = q; }
    __syncthreads();
    if (threadIdx.x < 2) {
        double t = (double)lds[0][threadIdx.x] + lds[1][threadIdx.x] + lds[2][threadIdx.x] + lds[3][threadIdx.x];
        atomicAdd(&dx[(blockIdx.x & (NBANK - 1)) * 2 + threadIdx.x], t);
    }
}

// ------- K2: lrelu(bn1(conv1(x))) -> conv2 (k2 s2) -> y2, + BN2 raw stats -------
// 1296 blocks x 256 threads, 2 adjacent positions per thread.
__global__ __launch_bounds__(256, 4) void k2_conv(const float* __restrict__ x,
                                                  const float* __restrict__ w1,
                                                  const float* __restrict__ g1,
                                                  const float* __restrict__ b1,
                                                  const float* __restrict__ w2,
                                                  const double* __restrict__ dx,
                                                  float* __restrict__ y2,
                                                  double* __restrict__ d2) {
    __shared__ __align__(16) float w2s[48 * 8];  // [c*16+m][8 (o padded)]
    __shared__ float p1s[6];                     // a1[3], c1[3]
    for (int idx = threadIdx.x; idx < 288; idx += 256) {
        int o = idx / 48, cm = idx % 48;
        w2s[cm * 8 + o] = w2[idx];
    }
    if (threadIdx.x < 3) {
        double sx = 0.0, qx = 0.0;
#pragma unroll
        for (int bk = 0; bk < NBANK; ++bk) { sx += dx[bk * 2]; qx += dx[bk * 2 + 1]; }
        double mux = sx / (double)NX;
        double vax = qx / (double)NX - mux * mux;
        int c = threadIdx.x;
        double w = (double)w1[c];
        double a = w * (double)g1[c] / sqrt(w * w * vax + EPS);
        p1s[c] = (float)a;
        p1s[3 + c] = (float)((double)b1[c] - mux * a);
    }
    __syncthreads();
    float a1[3], c1[3];
#pragma unroll
    for (int c = 0; c < 3; ++c) { a1[c] = p1s[c]; c1[c] = p1s[3 + c]; }

    int t = blockIdx.x * 256 + threadIdx.x;  // 0..331775
    int pos0 = t * 2;
    int b = pos0 / P2, rem = pos0 % P2;      // rem even
    int l0 = rem % 24, t1 = rem / 24;
    int k0 = t1 % 24, t2 = t1 / 24;
    int j0 = t2 % 24, i0 = t2 / 24;
    const float* xb = x + (size_t)b * P1 + (size_t)i0 * 221184 + j0 * 4608 + k0 * 96 + l0 * 2;

    f32x4 xq[8];
#pragma unroll
    for (int p = 0; p < 2; ++p)
#pragma unroll
        for (int q = 0; q < 2; ++q)
#pragma unroll
            for (int r = 0; r < 2; ++r)
                xq[p * 4 + q * 2 + r] = *(const f32x4*)(xb + p * 110592 + q * 2304 + r * 48);

    float acc0[6] = {0, 0, 0, 0, 0, 0}, acc1[6] = {0, 0, 0, 0, 0, 0};
#pragma unroll
    for (int pqr = 0; pqr < 8; ++pqr) {
#pragma unroll
        for (int s = 0; s < 2; ++s) {
            int m = pqr * 2 + s;
            float xs0 = xq[pqr][s];       // position pos0
            float xs1 = xq[pqr][2 + s];   // position pos0+1
#pragma unroll
            for (int c = 0; c < 3; ++c) {
                float tt0 = lrelu(a1[c] * xs0 + c1[c]);
                float tt1 = lrelu(a1[c] * xs1 + c1[c]);
                int base = (c * 16 + m) * 8;
                f32x4 w4 = *(const f32x4*)&w2s[base];
                f32x2 w2v = *(const f32x2*)&w2s[base + 4];
                acc0[0] += w4.x * tt0; acc1[0] += w4.x * tt1;
                acc0[1] += w4.y * tt0; acc1[1] += w4.y * tt1;
                acc0[2] += w4.z * tt0; acc1[2] += w4.z * tt1;
                acc0[3] += w4.w * tt0; acc1[3] += w4.w * tt1;
                acc0[4] += w2v.x * tt0; acc1[4] += w2v.x * tt1;
                acc0[5] += w2v.y * tt0; acc1[5] += w2v.y * tt1;
            }
        }
    }
    float sum[6], sq[6];
#pragma unroll
    for (int o = 0; o < 6; ++o) {
        f32x2 st; st.x = acc0[o]; st.y = acc1[o];
        *(f32x2*)(y2 + (size_t)(b * 6 + o) * P2 + rem) = st;
        sum[o] = acc0[o] + acc1[o];
        sq[o] = acc0[o] * acc0[o] + acc1[o] * acc1[o];
    }
    // block-reduce 12 floats, banked f64 atomics
    __shared__ float lds[4][12];
    int lane = threadIdx.x & 63, wv = threadIdx.x >> 6;
#pragma unroll
    for (int o = 0; o < 6; ++o) {
        float v = wredf(sum[o]); if (lane == 0) lds[wv][o] = v;
        v = wredf(sq[o]);        if (lane == 0) lds[wv][6 + o] = v;
    }
    __syncthreads();
    if (threadIdx.x < 12) {
        double t2d = (double)lds[0][threadIdx.x] + lds[1][threadIdx.x] + lds[2][threadIdx.x] + lds[3][threadIdx.x];
        atomicAdd(&d2[(blockIdx.x & (NBANK - 1)) * 12 + threadIdx.x], t2d);
    }
}

// ------- K3: Gram/S of y2n = lrelu(bn2(y2))  (for closed-form BN3 stats) -------
// 1296 blocks x 256 threads, 2 adjacent positions per thread.
__global__ __launch_bounds__(256, 4) void k3_gram(const float* __restrict__ y2,
                                                  const float* __restrict__ g2,
                                                  const float* __restrict__ b2,
                                                  const double* __restrict__ d2,
                                                  double* __restrict__ d3) {
    __shared__ float p2s[12];
    if (threadIdx.x < 6) {
        int c = threadIdx.x;
        double s = 0.0, q = 0.0;
#pragma unroll
        for (int bk = 0; bk < NBANK; ++bk) { s += d2[bk * 12 + c]; q += d2[bk * 12 + 6 + c]; }
        double mu = s / N2CH;
        double va = q / N2CH - mu * mu;
        double a = (double)g2[c] / sqrt(va + EPS);
        p2s[c] = (float)a;
        p2s[6 + c] = (float)((double)b2[c] - mu * a);
    }
    __syncthreads();
    float a2[6], c2[6];
#pragma unroll
    for (int c = 0; c < 6; ++c) { a2[c] = p2s[c]; c2[c] = p2s[6 + c]; }

    int t = blockIdx.x * 256 + threadIdx.x;
    int pos0 = t * 2;
    int b = pos0 / P2, rem = pos0 % P2;
    float yn0[6], yn1[6];
#pragma unroll
    for (int c = 0; c < 6; ++c) {
        f32x2 v = *(const f32x2*)(y2 + (size_t)(b * 6 + c) * P2 + rem);
        yn0[c] = lrelu(a2[c] * v.x + c2[c]);
        yn1[c] = lrelu(a2[c] * v.y + c2[c]);
    }
    float S[6], G[21];
#pragma unroll
    for (int c = 0; c < 6; ++c) S[c] = yn0[c] + yn1[c];
    {
        int gi = 0;
#pragma unroll
        for (int c = 0; c < 6; ++c)
#pragma unroll
            for (int cc = c; cc < 6; ++cc) { G[gi] = yn0[c] * yn0[cc] + yn1[c] * yn1[cc]; ++gi; }
    }
    __shared__ float lds[4][27];
    int lane = threadIdx.x & 63, wv = threadIdx.x >> 6;
#pragma unroll
    for (int i = 0; i < 6; ++i) { float v = wredf(S[i]); if (lane == 0) lds[wv][i] = v; }
#pragma unroll
    for (int i = 0; i < 21; ++i) { float v = wredf(G[i]); if (lane == 0) lds[wv][6 + i] = v; }
    __syncthreads();
    if (threadIdx.x < 27) {
        double td = (double)lds[0][threadIdx.x] + lds[1][threadIdx.x] + lds[2][threadIdx.x] + lds[3][threadIdx.x];
        atomicAdd(&d3[(blockIdx.x & (NBANK - 1)) * 27 + threadIdx.x], td);
    }
}

// ------- K4: finalize bn2 affine + closed-form BN3 affine (tiny) -------
__global__ void k4_params(const double* __restrict__ d2, const double* __restrict__ d3,
                          const float* __restrict__ wt,
                          const float* __restrict__ g2v, const float* __restrict__ b2v,
                          const float* __restrict__ g3, const float* __restrict__ b3,
                          float* __restrict__ params) {
    __shared__ double S[6], G[21], s2[12];
    int t = threadIdx.x;
    if (t < 27) {
        double a = 0.0;
        for (int bk = 0; bk < NBANK; ++bk) a += d3[bk * 27 + t];
        if (t < 6) S[t] = a; else G[t - 6] = a;
    }
    if (t >= 32 && t < 44) {
        double a = 0.0;
        for (int bk = 0; bk < NBANK; ++bk) a += d2[bk * 12 + (t - 32)];
        s2[t - 32] = a;
    }
    __syncthreads();
    if (t < 6) {
        int c = t;
        double mu = s2[c] / N2CH;
        double va = s2[6 + c] / N2CH - mu * mu;
        double a = (double)g2v[c] / sqrt(va + EPS);
        params[c] = (float)a;
        params[6 + c] = (float)((double)b2v[c] - mu * a);
    }
    if (t < 3) {
        int o = t;
        double sumz = 0.0, ssq = 0.0;
        for (int c = 0; c < 6; ++c) {
            double wsum = 0.0;
            for (int m = 0; m < 16; ++m) wsum += (double)wt[c * 48 + o * 16 + m];
            sumz += S[c] * wsum;
        }
        for (int c = 0; c < 6; ++c)
            for (int cc = 0; cc < 6; ++cc) {
                double ww = 0.0;
                for (int m = 0; m < 16; ++m) ww += (double)wt[c * 48 + o * 16 + m] * wt[cc * 48 + o * 16 + m];
                int aa = c < cc ? c : cc, bb = c < cc ? cc : c;
                int gidx = aa * 6 - aa * (aa + 1) / 2 + bb;
                ssq += G[gidx] * ww;
            }
        double mu = sumz / NZCH;
        double va = ssq / NZCH - mu * mu;
        double a = (double)g3[o] / sqrt(va + EPS);
        params[12 + o] = (float)a;
        params[15 + o] = (float)((double)b3[o] - mu * a);
    }
}

// ------- K5: row-mapped expand: bn2+lrelu -> convT -> bn3 -> sigmoid -> out -------
// Each thread: one output row (b,i,j,k), one float4 (l=4d..4d+3) for ALL 3 o.
// (p,q,r) fixed per thread -> only 36 wt weights, held in VGPRs.
__global__ __launch_bounds__(256) void k5_expand(const float* __restrict__ y2,
                                                 const float* __restrict__ wt,
                                                 const float* __restrict__ params,
                                                 float* __restrict__ out) {
    int t = blockIdx.x * 256 + threadIdx.x;   // 2654208 threads
    int row = t / 12, d = t % 12;
    int b = row / 110592, rr = row % 110592;
    int i = rr / 2304, r2 = rr % 2304;
    int j = r2 / 48, k = r2 % 48;
    int i0 = i >> 1, p = i & 1;
    int j0 = j >> 1, q = j & 1;
    int k0 = k >> 1, r = k & 1;

    float a2[6], c2[6], a3[3], c3[3];
#pragma unroll
    for (int c = 0; c < 6; ++c) { a2[c] = params[c]; c2[c] = params[6 + c]; }
#pragma unroll
    for (int o = 0; o < 3; ++o) { a3[o] = params[12 + o]; c3[o] = params[15 + o]; }

    // W[o][s][c]
    float W[3][2][6];
    int wbase = p * 8 + q * 4 + r * 2;
#pragma unroll
    for (int o = 0; o < 3; ++o)
#pragma unroll
        for (int s = 0; s < 2; ++s)
#pragma unroll
            for (int c = 0; c < 6; ++c)
                W[o][s][c] = wt[c * 48 + o * 16 + wbase + s];

    const float* yb = y2 + (size_t)b * 6 * P2 + (size_t)i0 * 13824 + j0 * 576 + k0 * 24 + 2 * d;
    float yn0[6], yn1[6];
#pragma unroll
    for (int c = 0; c < 6; ++c) {
        f32x2 v = *(const f32x2*)(yb + (size_t)c * P2);
        yn0[c] = lrelu(a2[c] * v.x + c2[c]);
        yn1[c] = lrelu(a2[c] * v.y + c2[c]);
    }

    size_t ob = (size_t)b * 15925248 + (size_t)i * 110592 + (size_t)j * 2304 + k * 48 + 4 * d;
#pragma unroll
    for (int o = 0; o < 3; ++o) {
        f32x4 res;
#pragma unroll
        for (int dd = 0; dd < 4; ++dd) {
            int s = dd & 1;
            float z = 0.f;
            if (dd < 2) {
#pragma unroll
                for (int c = 0; c < 6; ++c) z += yn0[c] * W[o][s][c];
            } else {
#pragma unroll
                for (int c = 0; c < 6; ++c) z += yn1[c] * W[o][s][c];
            }
            float v = a3[o] * z + c3[o];
            res[dd] = 1.f / (1.f + __expf(-v));
        }
        __builtin_nontemporal_store(res, (f32x4*)(out + ob + (size_t)o * P1));
    }
}

extern "C" void kernel_launch(void* const* d_in, const int* in_sizes, int n_in,
                              void* d_out, int out_size, void* d_ws, size_t ws_size,
                              hipStream_t stream) {
    const float* x  = (const float*)d_in[0];
    const float* w1 = (const float*)d_in[1];
    const float* g1 = (const float*)d_in[2];
    const float* b1 = (const float*)d_in[3];
    const float* w2 = (const float*)d_in[4];
    const float* g2 = (const float*)d_in[5];
    const float* b2 = (const float*)d_in[6];
    const float* wt = (const float*)d_in[7];
    const float* g3 = (const float*)d_in[8];
    const float* b3 = (const float*)d_in[9];
    float* out = (float*)d_out;

    char* ws = (char*)d_ws;
    double* dx     = (double*)(ws);
    double* d2     = (double*)(ws + 256);
    double* d3     = (double*)(ws + 1792);
    float*  params = (float*)(ws + 5248);
    float*  y2     = (float*)(ws + 8192);

    (void)hipMemsetAsync(d_ws, 0, 5248, stream);
    k1_stats_x<<<1296, 256, 0, stream>>>((const f32x4*)x, dx);
    k2_conv<<<1296, 256, 0, stream>>>(x, w1, g1, b1, w2, dx, y2, d2);
    k3_gram<<<1296, 256, 0, stream>>>(y2, g2, b2, d2, d3);
    k4_params<<<1, 64, 0, stream>>>(d2, d3, wt, g2, b2, g3, b3, params);
    k5_expand<<<10368, 256, 0, stream>>>(y2, wt, params, out);
}